// Round 9
// baseline (158.877 us; speedup 1.0000x reference)
//
#include <hip/hip_runtime.h>

typedef short short8 __attribute__((ext_vector_type(8)));
typedef float f32x4 __attribute__((ext_vector_type(4)));

#define HW 3136    // 56*56
#define NPX 12544  // B*HW
#define YSTR 96    // ytb row stride: 64 y + [1, 0..0] b2 lane
#define GS 54      // wgt group stride (ushorts): 49 taps + 5 pad (27 dw, odd-mixed banks)
#define PS 436     // wgt pixel stride (ushorts): 8*54 + 4; /4 = 109 b64-units (odd)
#define SEG 101    // xsb segment stride (uints)
#define WG_OFF 6464  // bytes: xsb = 16*101*4

__device__ __forceinline__ unsigned short f2bf(float f) {
    union { float f; unsigned int u; } v; v.f = f;
    unsigned int u = v.u;
    u += 0x7FFFu + ((u >> 16) & 1u);
    return (unsigned short)(u >> 16);
}

__device__ __forceinline__ float fget(const float4& v, int e) {
    return e == 0 ? v.x : e == 1 ? v.y : e == 2 ? v.z : v.w;
}

// Merged prep + y-GEMM.
// blocks 0..783: y = relu(bn(w1 @ x)) -> ytb[px][96] (w1 converted inline, BN inline)
// blocks 784..979: w2b96[ch][96] = bf16([w2 | b2 | 0..])
__global__ __launch_bounds__(256) void kyw(
    const float* __restrict__ x, const float* __restrict__ w1,
    const float* __restrict__ b1, const float* __restrict__ gamma,
    const float* __restrict__ beta, const float* __restrict__ mean,
    const float* __restrict__ var, const float* __restrict__ w2,
    const float* __restrict__ b2, unsigned short* __restrict__ ytb,
    unsigned short* __restrict__ w2b96)
{
    __shared__ unsigned short xt[16 * 264];    // [px][ch], stride 264
    const int t = threadIdx.x, bid = blockIdx.x;

    if (bid >= 784) {                          // w2 -> bf16 K=96 rows
        const int ch0 = (bid - 784) * 16;
#pragma unroll
        for (int i = 0; i < 6; ++i) {
            int j = i * 256 + t;               // 1536 = 16 ch * 96
            int ch = ch0 + j / 96, col = j - (j / 96) * 96;
            float v = col < 64 ? w2[ch * 64 + col] : (col == 64 ? b2[ch] : 0.f);
            w2b96[ch * 96 + col] = f2bf(v);
        }
        return;
    }

    const int px0 = bid * 16;
    const int b = px0 / HW;
    const int p0 = px0 - b * HW;

    // stage x tile: 16 px x 256 ch fp32 -> bf16 LDS (transposed to [px][ch])
#pragma unroll
    for (int i = 0; i < 4; ++i) {
        int j = i * 256 + t;                   // 1024 jobs: (c, pixel-quad)
        int c = j >> 2, pq = j & 3;
        float4 v = *(const float4*)(x + (size_t)(b * 256 + c) * HW + p0 + pq * 4);
        xt[(pq * 4 + 0) * 264 + c] = f2bf(v.x);
        xt[(pq * 4 + 1) * 264 + c] = f2bf(v.y);
        xt[(pq * 4 + 2) * 264 + c] = f2bf(v.z);
        xt[(pq * 4 + 3) * 264 + c] = f2bf(v.w);
    }
    // constant tail of ytb rows: [64]=1.0bf16, [65..95]=0
    if (t < 16) {
        unsigned short* yr = ytb + (size_t)(px0 + t) * YSTR + 64;
        ushort4 one; one.x = 0x3F80u; one.y = 0; one.z = 0; one.w = 0;
        ushort4 z; z.x = 0; z.y = 0; z.z = 0; z.w = 0;
        *(ushort4*)(yr) = one;
#pragma unroll
        for (int q = 1; q < 8; ++q) *(ushort4*)(yr + q * 4) = z;
    }
    __syncthreads();

    const int lane = t & 63, wave = t >> 6;
    const int n = lane & 15, quad = lane >> 4;
    const int m0 = wave * 16;

    f32x4 acc = {0.f, 0.f, 0.f, 0.f};
#pragma unroll
    for (int k = 0; k < 8; ++k) {
        const float* wrow = w1 + (m0 + n) * 256 + k * 32 + quad * 8;
        float4 wa = *(const float4*)(wrow);
        float4 wb = *(const float4*)(wrow + 4);
        short8 af;
        af[0] = (short)f2bf(wa.x); af[1] = (short)f2bf(wa.y);
        af[2] = (short)f2bf(wa.z); af[3] = (short)f2bf(wa.w);
        af[4] = (short)f2bf(wb.x); af[5] = (short)f2bf(wb.y);
        af[6] = (short)f2bf(wb.z); af[7] = (short)f2bf(wb.w);
        short8 bf = *(const short8*)(&xt[n * 264 + k * 32 + quad * 8]);
        acc = __builtin_amdgcn_mfma_f32_16x16x32_bf16(af, bf, acc, 0, 0, 0);
    }
    ushort4 pack;
    unsigned short pk[4];
#pragma unroll
    for (int r = 0; r < 4; ++r) {
        int m = m0 + quad * 4 + r;
        float sc = gamma[m] * rsqrtf(var[m] + 1e-5f);
        float sh = beta[m] - mean[m] * sc + b1[m] * sc;
        pk[r] = f2bf(fmaxf(acc[r] * sc + sh, 0.f));
    }
    pack.x = pk[0]; pack.y = pk[1]; pack.z = pk[2]; pack.w = pk[3];
    *(ushort4*)(ytb + (size_t)(px0 + n) * YSTR + m0 + quad * 4) = pack;
}

// One (batch, chunk-of-8-groups) per block. 20,416 B LDS -> 8 blocks/CU.
// grid (32,14,14): x=(b,chunk8) so line-sharing / halo-sharing blocks land
// on the same XCD (Delta-id % 8 == 0) for L2 write-combining + x reuse.
__global__ __launch_bounds__(256, 8) void kmain(
    const float* __restrict__ x, const unsigned short* __restrict__ w2b96,
    const unsigned short* __restrict__ ytb, float* __restrict__ out)
{
    __shared__ __align__(16) char smem[20416];
    unsigned int* xsb = (unsigned int*)smem;               // 16 seg * 101 u32 = 6464 B
    unsigned short* wgt = (unsigned short*)(smem + WG_OFF);// 16 px * 436 ush = 13952 B

    const int t = threadIdx.x;
    const int pix = t & 15, sub = t >> 4;
    const int lane = t & 63, wave = t >> 6;
    const int bc = blockIdx.x;
    const int b = bc >> 3, c8 = bc & 7;       // channels c8*32 .. +31 (8 groups)
    const int w0 = blockIdx.y * 4, h0 = blockIdx.z * 4;
    const int ph = pix >> 2, pw = pix & 3;
    const int h = h0 + ph, w = w0 + pw;
    const int n = lane & 15, quad = lane >> 4;

    // 1. prefetch x footprint: job (cpair, g, row), t<160: 2 channels x 12 cols
    const int jcp = t & 1, jg = (t >> 1) & 7, jr = t >> 4;
    float4 rv[2][3];
    if (t < 160) {
        int hh = h0 + jr - 3;
        if (hh >= 0 && hh < 56) {
            const float* src = x + ((size_t)b * 256 + c8 * 32 + jg * 4 + jcp * 2) * HW + hh * 56;
#pragma unroll
            for (int qq = 0; qq < 3; ++qq) {
                int col0 = w0 - 4 + qq * 4;
                if (col0 >= 0 && col0 + 3 <= 55) {
#pragma unroll
                    for (int ci = 0; ci < 2; ++ci)
                        rv[ci][qq] = *(const float4*)(src + ci * HW + col0);
                } else {
#pragma unroll
                    for (int ci = 0; ci < 2; ++ci) {
                        float tmp[4];
#pragma unroll
                        for (int e = 0; e < 4; ++e) {
                            int col = col0 + e;
                            tmp[e] = (col >= 0 && col <= 55) ? src[ci * HW + col] : 0.f;
                        }
                        rv[ci][qq] = make_float4(tmp[0], tmp[1], tmp[2], tmp[3]);
                    }
                }
            }
        } else {
#pragma unroll
            for (int qq = 0; qq < 3; ++qq)
#pragma unroll
                for (int ci = 0; ci < 2; ++ci)
                    rv[ci][qq] = make_float4(0.f, 0.f, 0.f, 0.f);
        }
    }

    // 2. B-fragments from ytb (K=96 incl. b2 lane)
    const int Pn = b * HW + (h0 + (n >> 2)) * 56 + w0 + (n & 3);
    const unsigned short* yrp = ytb + (size_t)Pn * YSTR + quad * 8;
    const short8 bf0 = *(const short8*)(yrp);
    const short8 bf1 = *(const short8*)(yrp + 32);
    const short8 bf2 = *(const short8*)(yrp + 64);

    // 3. zero wgt pad taps k=49..51 (read by the kq=12 b64 in involution)
    for (int i = t; i < 384; i += 256) {       // 16 px * 8 g * 3
        int p = i / 24, rem = i - p * 24;
        int g = rem / 3, kk = 49 + (rem - g * 3);
        wgt[p * PS + g * GS + kk] = 0;
    }

    // 4. commit footprint to LDS: xsb[(g*2+cp)*SEG + r*10 + s] = bf16x2
    if (t < 160) {
        unsigned int* dst = xsb + (jg * 2 + jcp) * SEG + jr * 10;
#pragma unroll
        for (int s = 0; s < 10; ++s) {
            int qq = (s + 1) >> 2, e = (s + 1) & 3;
            dst[s] = (unsigned int)f2bf(fget(rv[0][qq], e)) |
                     ((unsigned int)f2bf(fget(rv[1][qq], e)) << 16);
        }
    }

    // 5. weight generation: 392 ch (25 tiles, last 8 rows dead) x 16 px, K=96 MFMA
    const int c0 = c8 * 392;
    for (int tile = wave; tile < 25; tile += 4) {
        const unsigned short* ap = w2b96 + (size_t)(c0 + tile * 16 + n) * 96 + quad * 8;
        short8 af0 = *(const short8*)(ap);
        short8 af1 = *(const short8*)(ap + 32);
        short8 af2 = *(const short8*)(ap + 64);
        f32x4 acc = {0.f, 0.f, 0.f, 0.f};
        acc = __builtin_amdgcn_mfma_f32_16x16x32_bf16(af0, bf0, acc, 0, 0, 0);
        acc = __builtin_amdgcn_mfma_f32_16x16x32_bf16(af1, bf1, acc, 0, 0, 0);
        acc = __builtin_amdgcn_mfma_f32_16x16x32_bf16(af2, bf2, acc, 0, 0, 0);
        int rbase = tile * 16 + quad * 4;
#pragma unroll
        for (int r = 0; r < 4; ++r) {
            int chl = rbase + r;
            if (chl < 392) {
                int g = chl / 49;
                int kk = chl - g * 49;
                wgt[n * PS + g * GS + kk] = f2bf(acc[r]);
            }
        }
    }
    __syncthreads();    // the only barrier: xsb + wgt ready

    // 6. involution: thread = (pixel pix, group g, channel-pair cp)
    const int g = sub & 7, cp = sub >> 3;
    const unsigned short* wr = wgt + pix * PS + g * GS;
    const unsigned int* xr = xsb + (g * 2 + cp) * SEG;
    float a0 = 0.f, a1 = 0.f;
#pragma unroll
    for (int kq = 0; kq < 13; ++kq) {
        uint2 wp = *(const uint2*)(wr + kq * 4);
#pragma unroll
        for (int e = 0; e < 4; ++e) {
            int k = kq * 4 + e;
            if (k < 49) {
                unsigned int uw = (e < 2) ? wp.x : wp.y;
                unsigned int ub = (e & 1) ? (uw & 0xffff0000u) : (uw << 16);
                float wv = __uint_as_float(ub);
                int ki = k / 7, kj = k - ki * 7;       // compile-time
                unsigned int xv = xr[(ph + ki) * 10 + (pw + kj)];
                a0 += wv * __uint_as_float(xv << 16);
                a1 += wv * __uint_as_float(xv & 0xffff0000u);
            }
        }
    }
    size_t ob = ((size_t)b * 256 + c8 * 32 + g * 4 + cp * 2) * HW + h * 56 + w;
    out[ob] = a0;
    out[ob + HW] = a1;
}

extern "C" void kernel_launch(void* const* d_in, const int* in_sizes, int n_in,
                              void* d_out, int out_size, void* d_ws, size_t ws_size,
                              hipStream_t stream) {
    const float* x     = (const float*)d_in[0];
    const float* w1    = (const float*)d_in[1];
    const float* b1    = (const float*)d_in[2];
    const float* gamma = (const float*)d_in[3];
    const float* beta  = (const float*)d_in[4];
    const float* mean  = (const float*)d_in[5];
    const float* var   = (const float*)d_in[6];
    const float* w2    = (const float*)d_in[7];
    const float* b2    = (const float*)d_in[8];
    float* out = (float*)d_out;

    unsigned short* ytb   = (unsigned short*)d_ws;         // 12544*96 ush
    unsigned short* w2b96 = ytb + (size_t)NPX * YSTR;      // 3144*96 ush (8 rows slack
                                                           //  for tile-24 overread)
    hipLaunchKernelGGL(kyw, dim3(980), dim3(256), 0, stream,
                       x, w1, b1, gamma, beta, mean, var, w2, b2, ytb, w2b96);
    hipLaunchKernelGGL(kmain, dim3(32, 14, 14), dim3(256), 0, stream,
                       x, w2b96, ytb, out);
}

// Round 10
// 152.597 us; speedup vs baseline: 1.0412x; 1.0412x over previous
//
#include <hip/hip_runtime.h>

typedef short short8 __attribute__((ext_vector_type(8)));
typedef float f32x4 __attribute__((ext_vector_type(4)));

#define HW 3136    // 56*56
#define NPX 12544  // B*HW
#define YSTR 96    // ytb row stride: 64 y + [1, 0..0] b2 lane
#define GS 60      // wgt group stride (ushorts): 49 + 11 pad; 120 B (8B-aligned, 15 u64 odd)
#define PS 484     // wgt pixel stride (ushorts): 8*60 + 4; 968 B (121 u64, odd)
#define XROW 17    // xsb row stride (u32)
#define XSEG 142   // xsb segment stride (u32): 8*17+6; %32 = 14
#define XS_OFF 15488  // bytes: wgt = 16*484*2

__device__ __forceinline__ unsigned short f2bf(float f) {
    union { float f; unsigned int u; } v; v.f = f;
    unsigned int u = v.u;
    u += 0x7FFFu + ((u >> 16) & 1u);
    return (unsigned short)(u >> 16);
}

__device__ __forceinline__ float fget(const float4& v, int e) {
    return e == 0 ? v.x : e == 1 ? v.y : e == 2 ? v.z : v.w;
}

// Merged prep + y-GEMM.
// blocks 0..783: y = relu(bn(w1 @ x)) -> ytb[px][96] (w1 converted inline, BN inline)
// blocks 784..979: w2b96[ch][96] = bf16([w2 | b2 | 0..])
__global__ __launch_bounds__(256) void kyw(
    const float* __restrict__ x, const float* __restrict__ w1,
    const float* __restrict__ b1, const float* __restrict__ gamma,
    const float* __restrict__ beta, const float* __restrict__ mean,
    const float* __restrict__ var, const float* __restrict__ w2,
    const float* __restrict__ b2, unsigned short* __restrict__ ytb,
    unsigned short* __restrict__ w2b96)
{
    __shared__ unsigned short xt[16 * 264];    // [px][ch], stride 264
    const int t = threadIdx.x, bid = blockIdx.x;

    if (bid >= 784) {                          // w2 -> bf16 K=96 rows
        const int ch0 = (bid - 784) * 16;
#pragma unroll
        for (int i = 0; i < 6; ++i) {
            int j = i * 256 + t;               // 1536 = 16 ch * 96
            int ch = ch0 + j / 96, col = j - (j / 96) * 96;
            float v = col < 64 ? w2[ch * 64 + col] : (col == 64 ? b2[ch] : 0.f);
            w2b96[ch * 96 + col] = f2bf(v);
        }
        return;
    }

    const int px0 = bid * 16;
    const int b = px0 / HW;
    const int p0 = px0 - b * HW;

    // stage x tile: 16 px x 256 ch fp32 -> bf16 LDS (transposed to [px][ch])
#pragma unroll
    for (int i = 0; i < 4; ++i) {
        int j = i * 256 + t;                   // 1024 jobs: (c, pixel-quad)
        int c = j >> 2, pq = j & 3;
        float4 v = *(const float4*)(x + (size_t)(b * 256 + c) * HW + p0 + pq * 4);
        xt[(pq * 4 + 0) * 264 + c] = f2bf(v.x);
        xt[(pq * 4 + 1) * 264 + c] = f2bf(v.y);
        xt[(pq * 4 + 2) * 264 + c] = f2bf(v.z);
        xt[(pq * 4 + 3) * 264 + c] = f2bf(v.w);
    }
    // constant tail of ytb rows: [64]=1.0bf16, [65..95]=0
    if (t < 16) {
        unsigned short* yr = ytb + (size_t)(px0 + t) * YSTR + 64;
        ushort4 one; one.x = 0x3F80u; one.y = 0; one.z = 0; one.w = 0;
        ushort4 z; z.x = 0; z.y = 0; z.z = 0; z.w = 0;
        *(ushort4*)(yr) = one;
#pragma unroll
        for (int q = 1; q < 8; ++q) *(ushort4*)(yr + q * 4) = z;
    }
    __syncthreads();

    const int lane = t & 63, wave = t >> 6;
    const int n = lane & 15, quad = lane >> 4;
    const int m0 = wave * 16;

    f32x4 acc = {0.f, 0.f, 0.f, 0.f};
#pragma unroll
    for (int k = 0; k < 8; ++k) {
        const float* wrow = w1 + (m0 + n) * 256 + k * 32 + quad * 8;
        float4 wa = *(const float4*)(wrow);
        float4 wb = *(const float4*)(wrow + 4);
        short8 af;
        af[0] = (short)f2bf(wa.x); af[1] = (short)f2bf(wa.y);
        af[2] = (short)f2bf(wa.z); af[3] = (short)f2bf(wa.w);
        af[4] = (short)f2bf(wb.x); af[5] = (short)f2bf(wb.y);
        af[6] = (short)f2bf(wb.z); af[7] = (short)f2bf(wb.w);
        short8 bf = *(const short8*)(&xt[n * 264 + k * 32 + quad * 8]);
        acc = __builtin_amdgcn_mfma_f32_16x16x32_bf16(af, bf, acc, 0, 0, 0);
    }
    ushort4 pack;
    unsigned short pk[4];
#pragma unroll
    for (int r = 0; r < 4; ++r) {
        int m = m0 + quad * 4 + r;
        float sc = gamma[m] * rsqrtf(var[m] + 1e-5f);
        float sh = beta[m] - mean[m] * sc + b1[m] * sc;
        pk[r] = f2bf(fmaxf(acc[r] * sc + sh, 0.f));
    }
    pack.x = pk[0]; pack.y = pk[1]; pack.z = pk[2]; pack.w = pk[3];
    *(ushort4*)(ytb + (size_t)(px0 + n) * YSTR + m0 + quad * 4) = pack;
}

// One (batch, 8-group chunk) per block; 2x8 pixel tile for full-ish line writes.
// LDS 24576 B -> 6 blocks/CU. grid (32, 7, 28): x=(b,c8) so line-sharing /
// halo-sharing / w2-slice-sharing blocks land on the same XCD.
__global__ __launch_bounds__(256, 6) void kmain(
    const float* __restrict__ x, const unsigned short* __restrict__ w2b96,
    const unsigned short* __restrict__ ytb, float* __restrict__ out)
{
    __shared__ __align__(16) char smem[24576];
    unsigned short* wgt = (unsigned short*)smem;           // 16 px * 484 ush = 15488 B
    unsigned int* xsb = (unsigned int*)(smem + XS_OFF);    // 16 seg * 142 u32 = 9088 B

    const int t = threadIdx.x;
    const int pix = t & 15, sub = t >> 4;
    const int lane = t & 63, wave = t >> 6;
    const int bc = blockIdx.x;
    const int b = bc >> 3, c8 = bc & 7;       // channels c8*32 .. +31 (8 groups)
    const int w0 = blockIdx.y * 8, h0 = blockIdx.z * 2;
    const int ph = pix >> 3, pw = pix & 7;    // 2 rows x 8 cols
    const int h = h0 + ph, w = w0 + pw;
    const int n = lane & 15, quad = lane >> 4;

    // 1. B-fragments from ytb first (longest-latency loads, needed for w-gen)
    const int Pn = b * HW + (h0 + (n >> 3)) * 56 + w0 + (n & 7);
    const unsigned short* yrp = ytb + (size_t)Pn * YSTR + quad * 8;
    const short8 bf0 = *(const short8*)(yrp);
    const short8 bf1 = *(const short8*)(yrp + 32);
    const short8 bf2 = *(const short8*)(yrp + 64);

    // 2. stage x footprint: seg=(g,cp) x 8 rows; cols w0-3..w0+10.
    //    All f4 slots are 4-aligned: each is fully in-bounds or fully out -> select only.
    if (t < 128) {
        const int seg = t & 15, jr = t >> 4;
        const int jg = seg >> 1, jcp = seg & 1;
        const int hh = h0 + jr - 3;
        const bool rowok = (hh >= 0) && (hh < 56);
        const float* src = x + ((size_t)b * 256 + c8 * 32 + jg * 4 + jcp * 2) * HW + hh * 56;
        float4 va[2][4];
#pragma unroll
        for (int q = 0; q < 4; ++q) {
            int col0 = w0 - 4 + q * 4;
            bool ok = rowok && (col0 >= 0) && (col0 <= 52);
#pragma unroll
            for (int ci = 0; ci < 2; ++ci)
                va[ci][q] = ok ? *(const float4*)(src + ci * HW + col0)
                              : make_float4(0.f, 0.f, 0.f, 0.f);
        }
        unsigned int* dst = xsb + seg * XSEG + jr * XROW;
#pragma unroll
        for (int q = 0; q < 4; ++q)
#pragma unroll
            for (int e = 0; e < 4; ++e) {
                int c = q * 4 + e - 1;               // col index w0-3+c
                if (c >= 0 && c < 14)
                    dst[c] = (unsigned int)f2bf(fget(va[0][q], e)) |
                             ((unsigned int)f2bf(fget(va[1][q], e)) << 16);
            }
    }

    // 3. zero wgt pad taps k=49..51 (kq=12 uint2 covers 48..51)
    for (int i = t; i < 384; i += 256) {       // 16 px * 8 g * 3
        int p = i / 24, rem = i - p * 24;
        int g = rem / 3, kk = 49 + (rem - g * 3);
        wgt[p * PS + g * GS + kk] = 0;
    }

    // 4. weight generation: 392 ch (25 tiles, tail rows dead) x 16 px, K=96 MFMA
    const int c0 = c8 * 392;
    for (int tile = wave; tile < 25; tile += 4) {
        const unsigned short* ap = w2b96 + (size_t)(c0 + tile * 16 + n) * 96 + quad * 8;
        short8 af0 = *(const short8*)(ap);
        short8 af1 = *(const short8*)(ap + 32);
        short8 af2 = *(const short8*)(ap + 64);
        f32x4 acc = {0.f, 0.f, 0.f, 0.f};
        acc = __builtin_amdgcn_mfma_f32_16x16x32_bf16(af0, bf0, acc, 0, 0, 0);
        acc = __builtin_amdgcn_mfma_f32_16x16x32_bf16(af1, bf1, acc, 0, 0, 0);
        acc = __builtin_amdgcn_mfma_f32_16x16x32_bf16(af2, bf2, acc, 0, 0, 0);
        int rbase = tile * 16 + quad * 4;
#pragma unroll
        for (int r = 0; r < 4; ++r) {
            int chl = rbase + r;
            if (chl < 392) {
                int g = chl / 49;
                int kk = chl - g * 49;
                wgt[n * PS + g * GS + kk] = f2bf(acc[r]);
            }
        }
    }
    __syncthreads();    // the only barrier: xsb + wgt ready

    // 5. involution: thread = (pixel pix, group g, channel-pair cp)
    const int g = sub & 7, cp = sub >> 3;
    const unsigned short* wr = wgt + pix * PS + g * GS;
    const unsigned int* xr = xsb + (g * 2 + cp) * XSEG;
    float a0 = 0.f, a1 = 0.f;
#pragma unroll
    for (int kq = 0; kq < 13; ++kq) {
        uint2 wp = *(const uint2*)(wr + kq * 4);
#pragma unroll
        for (int e = 0; e < 4; ++e) {
            int k = kq * 4 + e;
            if (k < 49) {
                unsigned int uw = (e < 2) ? wp.x : wp.y;
                unsigned int ub = (e & 1) ? (uw & 0xffff0000u) : (uw << 16);
                float wv = __uint_as_float(ub);
                int ki = k / 7, kj = k - ki * 7;       // compile-time
                unsigned int xv = xr[(ph + ki) * XROW + (pw + kj)];
                a0 += wv * __uint_as_float(xv << 16);
                a1 += wv * __uint_as_float(xv & 0xffff0000u);
            }
        }
    }
    size_t ob = ((size_t)b * 256 + c8 * 32 + g * 4 + cp * 2) * HW + h * 56 + w;
    out[ob] = a0;
    out[ob + HW] = a1;
}

extern "C" void kernel_launch(void* const* d_in, const int* in_sizes, int n_in,
                              void* d_out, int out_size, void* d_ws, size_t ws_size,
                              hipStream_t stream) {
    const float* x     = (const float*)d_in[0];
    const float* w1    = (const float*)d_in[1];
    const float* b1    = (const float*)d_in[2];
    const float* gamma = (const float*)d_in[3];
    const float* beta  = (const float*)d_in[4];
    const float* mean  = (const float*)d_in[5];
    const float* var   = (const float*)d_in[6];
    const float* w2    = (const float*)d_in[7];
    const float* b2    = (const float*)d_in[8];
    float* out = (float*)d_out;

    unsigned short* ytb   = (unsigned short*)d_ws;         // 12544*96 ush
    unsigned short* w2b96 = ytb + (size_t)NPX * YSTR;      // 3144*96 ush (8 rows slack
                                                           //  for tile-24 overread)
    hipLaunchKernelGGL(kyw, dim3(980), dim3(256), 0, stream,
                       x, w1, b1, gamma, beta, mean, var, w2, b2, ytb, w2b96);
    hipLaunchKernelGGL(kmain, dim3(32, 7, 28), dim3(256), 0, stream,
                       x, w2b96, ytb, out);
}